// Round 4
// baseline (176.400 us; speedup 1.0000x reference)
//
#include <hip/hip_runtime.h>

#define N_CELL 8192
#define N_DRUG 4096

typedef float f32x4 __attribute__((ext_vector_type(4)));

// Output layout (floats):
//   0                       : agg_cell_lp [N_CELL][N_DRUG]
//   OFF1 = N_CELL*N_DRUG    : agg_drug_lp [N_DRUG][N_CELL]
//   OFF2 = 2*N_CELL*N_DRUG  : self_cell_lp [N_CELL][N_CELL]
//   OFF3 = OFF2 + N_CELL^2  : self_drug_lp [N_DRUG][N_DRUG]
static constexpr size_t OFF1 = (size_t)N_CELL * N_DRUG;
static constexpr size_t OFF2 = 2ull * N_CELL * N_DRUG;
static constexpr size_t OFF3 = OFF2 + (size_t)N_CELL * N_CELL;

// Phase 1: fused row+col sums. 512 blocks, tile = 64 rows x 1024 cols.
// Reads adj exactly once; leaves it hot in the Infinity Cache for phase 2.
__global__ __launch_bounds__(256) void sums_kernel(const float* __restrict__ adj,
                                                   float* __restrict__ rowsum,
                                                   float* __restrict__ colsum) {
    __shared__ float part[64][65];  // [row][16-col partial], pad 65 -> conflict-free
    int tid = threadIdx.x;
    int cb = blockIdx.x & 3;    // col block 0..3   -> 1024 cols
    int rb = blockIdx.x >> 2;   // row block 0..127 -> 64 rows
    int c0 = cb * 1024;
    int r0 = rb * 64;
    const f32x4* ap = reinterpret_cast<const f32x4*>(adj + (size_t)r0 * N_DRUG + c0) + tid;
    f32x4 cacc = {0.f, 0.f, 0.f, 0.f};
#pragma unroll 4
    for (int r = 0; r < 64; ++r) {
        f32x4 v = ap[(size_t)r * (N_DRUG / 4)];
        cacc += v;
        float h = (v.x + v.y) + (v.z + v.w);
        h += __shfl_down(h, 1, 64);
        h += __shfl_down(h, 2, 64);     // lanes ≡0 mod 4 hold 16-col partials
        if ((tid & 3) == 0) part[r][tid >> 2] = h;
    }
    __syncthreads();
    if (tid < 64) {                      // wave 0: finish 64 rows
        float s = 0.f;
#pragma unroll 8
        for (int j = 0; j < 64; ++j) s += part[tid][j];   // banks (tid+j)%32: conflict-free
        atomicAdd(&rowsum[r0 + tid], s); // 4 partials per row (one per col-block)
    }
    int c = c0 + tid * 4;
    atomicAdd(&colsum[c + 0], cacc.x);   // 128 partials per col (one per row-block)
    atomicAdd(&colsum[c + 1], cacc.y);
    atomicAdd(&colsum[c + 2], cacc.z);
    atomicAdd(&colsum[c + 3], cacc.w);
}

// Phase 2: 64x64 tile scale + transpose. adj read expected L3-hot (only 48 KB
// written since phase 1). nt f32x4 writes for both agg outputs.
__global__ __launch_bounds__(256) void scale_kernel(const float* __restrict__ adj,
                                                    const float* __restrict__ rowsum,
                                                    const float* __restrict__ colsum,
                                                    float* __restrict__ out) {
    __shared__ float tile[64][69];
    int tid = threadIdx.x;
    int tx = tid & 15;   // 16 x f32x4 = 64 cols
    int ty = tid >> 4;   // 16 rows per pass
    int c0 = blockIdx.x * 64;
    int r0 = blockIdx.y * 64;

    f32x4 cs = *reinterpret_cast<const f32x4*>(colsum + c0 + tx * 4);
    f32x4 dy;
    dy.x = rsqrtf(cs.x + 1.0f);
    dy.y = rsqrtf(cs.y + 1.0f);
    dy.z = rsqrtf(cs.z + 1.0f);
    dy.w = rsqrtf(cs.w + 1.0f);

#pragma unroll
    for (int q = 0; q < 4; ++q) {
        int rr = q * 16 + ty;
        int r = r0 + rr;
        float dx = rsqrtf(rowsum[r] + 1.0f);
        f32x4 v = *reinterpret_cast<const f32x4*>(adj + (size_t)r * N_DRUG + c0 + tx * 4);
        f32x4 o = v * dx;
        o *= dy;
        __builtin_nontemporal_store(
            o, reinterpret_cast<f32x4*>(out + (size_t)r * N_DRUG + c0 + tx * 4));
        tile[rr][tx * 4 + 0] = o.x;
        tile[rr][tx * 4 + 1] = o.y;
        tile[rr][tx * 4 + 2] = o.z;
        tile[rr][tx * 4 + 3] = o.w;
    }
    __syncthreads();
    float* aggd = out + OFF1;
#pragma unroll
    for (int q = 0; q < 4; ++q) {
        int dr = q * 16 + ty;  // drug index within tile
        f32x4 o;
        o.x = tile[tx * 4 + 0][dr];
        o.y = tile[tx * 4 + 1][dr];
        o.z = tile[tx * 4 + 2][dr];
        o.w = tile[tx * 4 + 3][dr];
        __builtin_nontemporal_store(
            o, reinterpret_cast<f32x4*>(aggd + (size_t)(c0 + dr) * N_CELL + r0 + tx * 4));
    }
}

// Phase 4: diagonal values (after the big zero-fill).
__global__ __launch_bounds__(256) void diag_kernel(const float* __restrict__ rowsum,
                                                   const float* __restrict__ colsum,
                                                   float* __restrict__ out) {
    int i = blockIdx.x * 256 + threadIdx.x;
    if (i < N_CELL) {
        out[OFF2 + (size_t)i * (N_CELL + 1)] = 1.0f / (rowsum[i] + 1.0f) + 1.0f;
    } else if (i < N_CELL + N_DRUG) {
        int j = i - N_CELL;
        out[OFF3 + (size_t)j * (N_DRUG + 1)] = 1.0f / (colsum[j] + 1.0f) + 1.0f;
    }
}

extern "C" void kernel_launch(void* const* d_in, const int* in_sizes, int n_in,
                              void* d_out, int out_size, void* d_ws, size_t ws_size,
                              hipStream_t stream) {
    const float* adj = (const float*)d_in[0];
    float* out = (float*)d_out;
    float* rowsum = (float*)d_ws;        // N_CELL floats
    float* colsum = rowsum + N_CELL;     // N_DRUG floats

    // zero the atomic accumulators (contiguous 48 KB)
    (void)hipMemsetAsync(d_ws, 0, (N_CELL + N_DRUG) * sizeof(float), stream);

    sums_kernel<<<512, 256, 0, stream>>>(adj, rowsum, colsum);
    scale_kernel<<<dim3(N_DRUG / 64, N_CELL / 64), 256, 0, stream>>>(adj, rowsum, colsum, out);

    // Big zero-fill LAST so it cannot evict adj between phases 1 and 2.
    // Contiguous region: both self matrices = 335,544,320 bytes.
    (void)hipMemsetAsync(out + OFF2,
                         0,
                         ((size_t)N_CELL * N_CELL + (size_t)N_DRUG * N_DRUG) * sizeof(float),
                         stream);
    diag_kernel<<<48, 256, 0, stream>>>(rowsum, colsum, out);
}

// Round 6
// 174.308 us; speedup vs baseline: 1.0120x; 1.0120x over previous
//
#include <hip/hip_runtime.h>

#define N_CELL 8192
#define N_DRUG 4096

typedef float f32x4 __attribute__((ext_vector_type(4)));

// Output layout (floats):
//   0                       : agg_cell_lp [N_CELL][N_DRUG]
//   OFF1 = N_CELL*N_DRUG    : agg_drug_lp [N_DRUG][N_CELL]
//   OFF2 = 2*N_CELL*N_DRUG  : self_cell_lp [N_CELL][N_CELL]
//   OFF3 = OFF2 + N_CELL^2  : self_drug_lp [N_DRUG][N_DRUG]
static constexpr size_t OFF1 = (size_t)N_CELL * N_DRUG;
static constexpr size_t OFF2 = 2ull * N_CELL * N_DRUG;
static constexpr size_t OFF3 = OFF2 + (size_t)N_CELL * N_CELL;
static constexpr size_t FILL_F4 = ((size_t)N_CELL * N_CELL + (size_t)N_DRUG * N_DRUG) / 4; // 20,971,520

// ---- Dispatch 1: zero-fill both self matrices. 2048 blocks x 10240 f4 =
// 160 KB contiguous per block, nt stores (pure-write stream, ~6.5 TB/s). ----
#define FILL_BLOCKS 2048
static constexpr size_t FILL_PER_BLOCK = FILL_F4 / FILL_BLOCKS;  // 10240 f4 = 40/thread

__global__ __launch_bounds__(256) void fill_kernel(float* __restrict__ fill_base) {
    f32x4 z = {0.f, 0.f, 0.f, 0.f};
    f32x4* p = reinterpret_cast<f32x4*>(fill_base) + (size_t)blockIdx.x * FILL_PER_BLOCK;
#pragma unroll 4
    for (size_t i = threadIdx.x; i < FILL_PER_BLOCK; i += 256) {
        __builtin_nontemporal_store(z, p + i);
    }
}

// ---- Dispatch 2: fused row+col sums. 512 blocks, tile = 64 rows x 1024 cols.
// Reads adj exactly once -> allocates it in the Infinity Cache for dispatch 3. ----
__global__ __launch_bounds__(256) void sums_kernel(const float* __restrict__ adj,
                                                   float* __restrict__ rowsum,
                                                   float* __restrict__ colsum) {
    __shared__ float part[64][65];
    int tid = threadIdx.x;
    int cb = blockIdx.x & 3;    // col block 0..3   -> 1024 cols
    int rb = blockIdx.x >> 2;   // row block 0..127 -> 64 rows
    int c0 = cb * 1024;
    int r0 = rb * 64;
    const f32x4* ap = reinterpret_cast<const f32x4*>(adj + (size_t)r0 * N_DRUG + c0) + tid;
    f32x4 cacc = {0.f, 0.f, 0.f, 0.f};
#pragma unroll 4
    for (int r = 0; r < 64; ++r) {
        f32x4 v = ap[(size_t)r * (N_DRUG / 4)];
        cacc += v;
        float h = (v.x + v.y) + (v.z + v.w);
        h += __shfl_down(h, 1, 64);
        h += __shfl_down(h, 2, 64);     // lanes ≡0 mod 4 hold 16-col partials
        if ((tid & 3) == 0) part[r][tid >> 2] = h;
    }
    __syncthreads();
    if (tid < 64) {
        float s = 0.f;
#pragma unroll 8
        for (int j = 0; j < 64; ++j) s += part[tid][j];
        atomicAdd(&rowsum[r0 + tid], s);  // 4 partials per row
    }
    int c = c0 + tid * 4;
    atomicAdd(&colsum[c + 0], cacc.x);    // 128 partials per col
    atomicAdd(&colsum[c + 1], cacc.y);
    atomicAdd(&colsum[c + 2], cacc.z);
    atomicAdd(&colsum[c + 3], cacc.w);
}

// ---- Dispatch 3: scale+transpose on 128x128 tiles (four 64x64 LDS passes;
// output chunks are 2x256B adjacent = 512B DRAM locality) + 48 diag blocks. ----
#define DIAG_BLOCKS 48   // 48*256 = 12288 = N_CELL + N_DRUG diag elements
__global__ __launch_bounds__(256) void scale_kernel(const float* __restrict__ adj,
                                                    const float* __restrict__ rowsum,
                                                    const float* __restrict__ colsum,
                                                    float* __restrict__ out) {
    int tid = threadIdx.x;
    int b = blockIdx.x;
    if (b < DIAG_BLOCKS) {   // diagonal values (fill already completed in dispatch 1)
        int idx = b * 256 + tid;
        if (idx < N_CELL) {
            out[OFF2 + (size_t)idx * (N_CELL + 1)] = 1.0f / (rowsum[idx] + 1.0f) + 1.0f;
        } else {
            int k = idx - N_CELL;   // k < N_DRUG by construction (12288 total)
            out[OFF3 + (size_t)k * (N_DRUG + 1)] = 1.0f / (colsum[k] + 1.0f) + 1.0f;
        }
        return;
    }
    __shared__ float lds[64][69];
    int t = b - DIAG_BLOCKS;
    int tx = tid & 15;   // 16 x f32x4 = 64 cols
    int ty = tid >> 4;   // 16 rows per pass
    int c0 = (t & 31) * 128;   // 32 col-tiles
    int r0 = (t >> 5) * 128;   // 64 row-tiles
    float* aggd = out + OFF1;
#pragma unroll
    for (int s = 0; s < 4; ++s) {
        int cc = c0 + (s & 1) * 64;
        int rr0 = r0 + (s >> 1) * 64;
        f32x4 cs = *reinterpret_cast<const f32x4*>(colsum + cc + tx * 4);
        f32x4 dy;
        dy.x = rsqrtf(cs.x + 1.0f);
        dy.y = rsqrtf(cs.y + 1.0f);
        dy.z = rsqrtf(cs.z + 1.0f);
        dy.w = rsqrtf(cs.w + 1.0f);
#pragma unroll
        for (int q = 0; q < 4; ++q) {
            int rr = q * 16 + ty;
            int r = rr0 + rr;
            float dx = rsqrtf(rowsum[r] + 1.0f);
            f32x4 v = *reinterpret_cast<const f32x4*>(adj + (size_t)r * N_DRUG + cc + tx * 4);
            f32x4 o = v * dx;
            o *= dy;
            __builtin_nontemporal_store(
                o, reinterpret_cast<f32x4*>(out + (size_t)r * N_DRUG + cc + tx * 4));
            lds[rr][tx * 4 + 0] = o.x;
            lds[rr][tx * 4 + 1] = o.y;
            lds[rr][tx * 4 + 2] = o.z;
            lds[rr][tx * 4 + 3] = o.w;
        }
        __syncthreads();
#pragma unroll
        for (int q = 0; q < 4; ++q) {
            int dr = q * 16 + ty;
            f32x4 o;
            o.x = lds[tx * 4 + 0][dr];
            o.y = lds[tx * 4 + 1][dr];
            o.z = lds[tx * 4 + 2][dr];
            o.w = lds[tx * 4 + 3][dr];
            __builtin_nontemporal_store(
                o, reinterpret_cast<f32x4*>(aggd + (size_t)(cc + dr) * N_CELL + rr0 + tx * 4));
        }
        __syncthreads();   // before next sub-tile reuses lds
    }
}

extern "C" void kernel_launch(void* const* d_in, const int* in_sizes, int n_in,
                              void* d_out, int out_size, void* d_ws, size_t ws_size,
                              hipStream_t stream) {
    const float* adj = (const float*)d_in[0];
    float* out = (float*)d_out;
    float* rowsum = (float*)d_ws;        // N_CELL floats
    float* colsum = rowsum + N_CELL;     // N_DRUG floats

    // zero the atomic accumulators (contiguous 48 KB)
    (void)hipMemsetAsync(d_ws, 0, (N_CELL + N_DRUG) * sizeof(float), stream);

    // 1) big zero-fill FIRST (pure write, nothing between adj read1 and read2)
    fill_kernel<<<FILL_BLOCKS, 256, 0, stream>>>(out + OFF2);
    // 2) sums: adj -> Infinity Cache
    sums_kernel<<<512, 256, 0, stream>>>(adj, rowsum, colsum);
    // 3) scale+transpose (adj hopefully MALL-hot) + diag
    scale_kernel<<<DIAG_BLOCKS + 2048, 256, 0, stream>>>(adj, rowsum, colsum, out);
}

// Round 7
// 153.161 us; speedup vs baseline: 1.1517x; 1.1381x over previous
//
#include <hip/hip_runtime.h>

#define N_CELL 8192
#define N_DRUG 4096

typedef float f32x4 __attribute__((ext_vector_type(4)));

// Output layout (floats):
//   0                       : agg_cell_lp [N_CELL][N_DRUG]
//   OFF1 = N_CELL*N_DRUG    : agg_drug_lp [N_DRUG][N_CELL]
//   OFF2 = 2*N_CELL*N_DRUG  : self_cell_lp [N_CELL][N_CELL]
//   OFF3 = OFF2 + N_CELL^2  : self_drug_lp [N_DRUG][N_DRUG]
static constexpr size_t OFF1 = (size_t)N_CELL * N_DRUG;
static constexpr size_t OFF2 = 2ull * N_CELL * N_DRUG;
static constexpr size_t OFF3 = OFF2 + (size_t)N_CELL * N_CELL;
static constexpr size_t FILL_F4 = ((size_t)N_CELL * N_CELL + (size_t)N_DRUG * N_DRUG) / 4; // 20,971,520

// ---- D1: 512 sums blocks + 1280 fill blocks, per-block work balanced at 262 KB ----
#define SUM_BLOCKS 512
#define FILL_BLOCKS 1280
#define MEGA_BLOCKS (SUM_BLOCKS + FILL_BLOCKS)          // 1792 = 7 blocks/CU
static constexpr size_t FILL_PER_BLOCK = FILL_F4 / FILL_BLOCKS;  // 16384 f4 = 256KB, exact

__global__ __launch_bounds__(256, 8) void mega_kernel(const float* __restrict__ adj,
                                                      float* __restrict__ rowsum,
                                                      float* __restrict__ colsum,
                                                      float* __restrict__ fill_base) {
    int b = blockIdx.x;
    int tid = threadIdx.x;
    if (b >= SUM_BLOCKS) {
        // nt zero-fill: 16384 f4 contiguous per block (256 KB)
        f32x4 z = {0.f, 0.f, 0.f, 0.f};
        f32x4* p = reinterpret_cast<f32x4*>(fill_base) + (size_t)(b - SUM_BLOCKS) * FILL_PER_BLOCK;
#pragma unroll 4
        for (size_t i = tid; i < FILL_PER_BLOCK; i += 256) {
            __builtin_nontemporal_store(z, p + i);
        }
        return;
    }
    // sums role: 64 rows x 1024 cols
    __shared__ float part[64][65];
    int cb = b & 3, rb = b >> 2;
    int c0 = cb * 1024, r0 = rb * 64;
    const f32x4* ap = reinterpret_cast<const f32x4*>(adj + (size_t)r0 * N_DRUG + c0) + tid;
    f32x4 cacc = {0.f, 0.f, 0.f, 0.f};
#pragma unroll 4
    for (int r = 0; r < 64; ++r) {
        f32x4 v = ap[(size_t)r * (N_DRUG / 4)];
        cacc += v;
        float h = (v.x + v.y) + (v.z + v.w);
        h += __shfl_down(h, 1, 64);
        h += __shfl_down(h, 2, 64);     // lanes ≡0 mod 4 hold 16-col partials
        if ((tid & 3) == 0) part[r][tid >> 2] = h;
    }
    __syncthreads();
    if (tid < 64) {
        float s = 0.f;
#pragma unroll 8
        for (int j = 0; j < 64; ++j) s += part[tid][j];
        atomicAdd(&rowsum[r0 + tid], s);  // 4 partials per row
    }
    int c = c0 + tid * 4;
    atomicAdd(&colsum[c + 0], cacc.x);    // 128 partials per col
    atomicAdd(&colsum[c + 1], cacc.y);
    atomicAdd(&colsum[c + 2], cacc.z);
    atomicAdd(&colsum[c + 3], cacc.w);
}

// ---- D2: scale+transpose on 128x128 tiles (512B write chunks both outputs),
// s-loop kept rolled to bound VGPR; occupancy pinned at 8 blocks/CU. ----
#define SCALE_TILES 2048   // 32 col-tiles x 64 row-tiles
#define DIAG_BLOCKS 48     // 48*256 = 12288 = N_CELL + N_DRUG
__global__ __launch_bounds__(256, 8) void scale_kernel(const float* __restrict__ adj,
                                                       const float* __restrict__ rowsum,
                                                       const float* __restrict__ colsum,
                                                       float* __restrict__ out) {
    int tid = threadIdx.x;
    int b = blockIdx.x;
    if (b >= SCALE_TILES) {  // diag role (fill completed in D1)
        int idx = (b - SCALE_TILES) * 256 + tid;
        if (idx < N_CELL) {
            out[OFF2 + (size_t)idx * (N_CELL + 1)] = 1.0f / (rowsum[idx] + 1.0f) + 1.0f;
        } else {
            int k = idx - N_CELL;   // < N_DRUG by construction
            out[OFF3 + (size_t)k * (N_DRUG + 1)] = 1.0f / (colsum[k] + 1.0f) + 1.0f;
        }
        return;
    }
    __shared__ float lds[64][69];
    int tx = tid & 15;   // 16 x f32x4 = 64 cols
    int ty = tid >> 4;   // 16 rows per pass
    int c0 = (b & 31) * 128;   // 32 col-tiles
    int r0 = (b >> 5) * 128;   // 64 row-tiles
    float* aggd = out + OFF1;
#pragma unroll 1
    for (int s = 0; s < 4; ++s) {
        int cc = c0 + (s & 1) * 64;
        int rr0 = r0 + (s >> 1) * 64;
        f32x4 cs = *reinterpret_cast<const f32x4*>(colsum + cc + tx * 4);
        f32x4 dy;
        dy.x = rsqrtf(cs.x + 1.0f);
        dy.y = rsqrtf(cs.y + 1.0f);
        dy.z = rsqrtf(cs.z + 1.0f);
        dy.w = rsqrtf(cs.w + 1.0f);
#pragma unroll
        for (int q = 0; q < 4; ++q) {
            int rr = q * 16 + ty;
            int r = rr0 + rr;
            float dx = rsqrtf(rowsum[r] + 1.0f);
            f32x4 v = *reinterpret_cast<const f32x4*>(adj + (size_t)r * N_DRUG + cc + tx * 4);
            f32x4 o = v * dx;
            o *= dy;
            __builtin_nontemporal_store(
                o, reinterpret_cast<f32x4*>(out + (size_t)r * N_DRUG + cc + tx * 4));
            lds[rr][tx * 4 + 0] = o.x;
            lds[rr][tx * 4 + 1] = o.y;
            lds[rr][tx * 4 + 2] = o.z;
            lds[rr][tx * 4 + 3] = o.w;
        }
        __syncthreads();
#pragma unroll
        for (int q = 0; q < 4; ++q) {
            int dr = q * 16 + ty;
            f32x4 o;
            o.x = lds[tx * 4 + 0][dr];
            o.y = lds[tx * 4 + 1][dr];
            o.z = lds[tx * 4 + 2][dr];
            o.w = lds[tx * 4 + 3][dr];
            __builtin_nontemporal_store(
                o, reinterpret_cast<f32x4*>(aggd + (size_t)(cc + dr) * N_CELL + rr0 + tx * 4));
        }
        __syncthreads();   // before next sub-tile reuses lds
    }
}

extern "C" void kernel_launch(void* const* d_in, const int* in_sizes, int n_in,
                              void* d_out, int out_size, void* d_ws, size_t ws_size,
                              hipStream_t stream) {
    const float* adj = (const float*)d_in[0];
    float* out = (float*)d_out;
    float* rowsum = (float*)d_ws;        // N_CELL floats
    float* colsum = rowsum + N_CELL;     // N_DRUG floats

    // zero the atomic accumulators (contiguous 48 KB)
    (void)hipMemsetAsync(d_ws, 0, (N_CELL + N_DRUG) * sizeof(float), stream);

    mega_kernel<<<MEGA_BLOCKS, 256, 0, stream>>>(adj, rowsum, colsum, out + OFF2);
    scale_kernel<<<SCALE_TILES + DIAG_BLOCKS, 256, 0, stream>>>(adj, rowsum, colsum, out);
}